// Round 1
// baseline (398.214 us; speedup 1.0000x reference)
//
#include <hip/hip_runtime.h>

#define BATCH   8
#define NNODE   2048
#define CH      256
#define NEDGE   32768
#define NLAYER  3
#define MROWS   (NNODE*BATCH)      // 16384 rows (n-major: row = n*8 + b)
#define KCAT    (3*CH)             // 768
#define NTOT    (MROWS*CH)         // 4,194,304 elements of h

typedef _Float16 half8 __attribute__((ext_vector_type(8)));
typedef _Float16 half4 __attribute__((ext_vector_type(4)));
typedef float    f32x4 __attribute__((ext_vector_type(4)));

// ---------------- workspace layout (bytes) ----------------
#define OFF_H      ((size_t)0)                    // fp32 h [MROWS][CH]            16,777,216
#define OFF_ACAT   ((size_t)16777216)             // f16 Acat [MROWS][KCAT]        25,165,824
#define OFF_WT     ((size_t)(16777216+25165824))  // f16 Wt [3][CH][KCAT]           1,179,648
#define OFF_MT     (OFF_WT + 1179648)             // f16 Mt [3][CH][CH]               393,216
#define OFF_PART   (OFF_MT + 393216)              // float2 part[1024]                  8,192
#define OFF_DEG    (OFF_PART + 8192)              // f32 deg[3][NNODE]                 24,576
#define OFF_CNT    (OFF_DEG + 24576)              // u32 count[3][NNODE]               24,576
#define OFF_ELIST  (OFF_CNT + 24576)              // u32 elist[3][NNODE][64]        1,572,864
#define OFF_NORM   (OFF_ELIST + 1572864)          // f32 norm[3][NEDGE]               393,216
#define OFF_MP     (OFF_NORM + 393216)            // f32 meanpart[8][64][CH]          524,288
// total ~46.1 MB

__device__ __forceinline__ void async_lds16(const void* g, void* l) {
  __builtin_amdgcn_global_load_lds((const __attribute__((address_space(1))) void*)g,
                                   (__attribute__((address_space(3))) void*)l, 16, 0, 0);
}

// ---- transpose [B,N,C] -> [N,B,C] fp32, fused stats partials for layer-0 LN1 ----
__global__ __launch_bounds__(256) void k_transpose(const float* __restrict__ x,
                                                   float* __restrict__ h,
                                                   float2* __restrict__ part) {
  int tid = blockIdx.x*256 + threadIdx.x;
  float s = 0.f, s2 = 0.f;
  for (int i = tid; i < NTOT/4; i += 1024*256) {
    int c4 = i & 63, b = (i >> 6) & 7, n = i >> 9;
    float4 v = ((const float4*)x)[((b*NNODE + n) << 6) + c4];
    ((float4*)h)[i] = v;
    s  += v.x + v.y + v.z + v.w;
    s2 += v.x*v.x + v.y*v.y + v.z*v.z + v.w*v.w;
  }
  __shared__ float rs[512];
  rs[threadIdx.x] = s; rs[256+threadIdx.x] = s2; __syncthreads();
  for (int o = 128; o > 0; o >>= 1) {
    if (threadIdx.x < o) { rs[threadIdx.x] += rs[threadIdx.x+o]; rs[256+threadIdx.x] += rs[256+threadIdx.x+o]; }
    __syncthreads();
  }
  if (threadIdx.x == 0) part[blockIdx.x] = make_float2(rs[0], rs[256]);
}

// ---- convert weights to f16, transposed to n-major [n][k] ----
__global__ __launch_bounds__(256) void k_weights(const float* __restrict__ cheb_w,
                                                 const float* __restrict__ mlp_w,
                                                 _Float16* __restrict__ Wt,
                                                 _Float16* __restrict__ Mt) {
  int i = blockIdx.x*256 + threadIdx.x;
  const int nc = NLAYER*CH*KCAT;  // 589,824
  if (i < nc) {
    int l = i / (CH*KCAT), r = i % (CH*KCAT);
    int n = r / KCAT, k = r % KCAT;
    int kk = k >> 8, cin = k & 255;
    Wt[i] = (_Float16)cheb_w[((l*3 + kk)*CH + cin)*CH + n];
  } else {
    int j = i - nc;
    if (j < NLAYER*CH*CH) {
      int l = j / (CH*CH), r = j % (CH*CH);
      int n = r >> 8, k = r & 255;
      Mt[j] = (_Float16)mlp_w[(l*CH + k)*CH + n];
    }
  }
}

// ---- edge preprocessing (all 3 layers at once) ----
__global__ __launch_bounds__(256) void k_edge_zero(float* deg, unsigned int* count) {
  int i = blockIdx.x*256 + threadIdx.x;
  if (i < NLAYER*NNODE) { deg[i] = 0.f; count[i] = 0u; }
}

__global__ __launch_bounds__(256) void k_edge_scatter(const int* __restrict__ ei,
                                                      const float* __restrict__ ew,
                                                      float* deg, unsigned int* count,
                                                      unsigned int* elist) {
  int i = blockIdx.x*256 + threadIdx.x;
  if (i >= NLAYER*NEDGE) return;
  int l = i / NEDGE, e = i % NEDGE;
  const int* rows = ei + l*2*NEDGE;
  const int* cols = rows + NEDGE;
  int r = rows[e], c = cols[e];
  float w = (r == c) ? 0.f : ew[l*NEDGE + e];
  atomicAdd(&deg[l*NNODE + r], w);
  unsigned int slot = atomicAdd(&count[l*NNODE + c], 1u);
  if (slot < 64u) elist[(l*NNODE + c)*64 + slot] = (unsigned int)e;
}

__global__ __launch_bounds__(256) void k_edge_norm(const int* __restrict__ ei,
                                                   const float* __restrict__ ew,
                                                   const float* __restrict__ deg,
                                                   float* __restrict__ norm) {
  int i = blockIdx.x*256 + threadIdx.x;
  if (i >= NLAYER*NEDGE) return;
  int l = i / NEDGE, e = i % NEDGE;
  const int* rows = ei + l*2*NEDGE;
  const int* cols = rows + NEDGE;
  int r = rows[e], c = cols[e];
  float w = (r == c) ? 0.f : ew[l*NEDGE + e];
  float dr = deg[l*NNODE + r], dc = deg[l*NNODE + c];
  float ir = dr > 0.f ? rsqrtf(fmaxf(dr, 1e-12f)) : 0.f;
  float ic = dc > 0.f ? rsqrtf(fmaxf(dc, 1e-12f)) : 0.f;
  norm[i] = -(ir * w * ic);
}

// ---- whole-tensor LN: reduce 1024 partials, write f16 hn into Acat[:,0:256] ----
__global__ __launch_bounds__(256) void k_ln(const float* __restrict__ h,
                                            const float2* __restrict__ part,
                                            _Float16* __restrict__ Acat) {
  __shared__ float red[512];
  float s = 0.f, s2 = 0.f;
  for (int i = threadIdx.x; i < 1024; i += 256) { float2 p = part[i]; s += p.x; s2 += p.y; }
  red[threadIdx.x] = s; red[256+threadIdx.x] = s2; __syncthreads();
  for (int o = 128; o > 0; o >>= 1) {
    if (threadIdx.x < o) { red[threadIdx.x] += red[threadIdx.x+o]; red[256+threadIdx.x] += red[256+threadIdx.x+o]; }
    __syncthreads();
  }
  __shared__ float mv[2];
  if (threadIdx.x == 0) {
    float mean = red[0] * (1.f/(float)NTOT);
    float var  = red[256] * (1.f/(float)NTOT) - mean*mean;
    mv[0] = mean; mv[1] = rsqrtf(var + 1e-5f);
  }
  __syncthreads();
  const float mean = mv[0], istd = mv[1];
  const float4* h4 = (const float4*)h;
  for (int i = blockIdx.x*256 + threadIdx.x; i < NTOT/4; i += 1024*256) {
    float4 v = h4[i];
    int r = i >> 6, c4 = i & 63;
    half4 o;
    o[0] = (_Float16)((v.x - mean)*istd);
    o[1] = (_Float16)((v.y - mean)*istd);
    o[2] = (_Float16)((v.z - mean)*istd);
    o[3] = (_Float16)((v.w - mean)*istd);
    *(half4*)&Acat[(size_t)r*KCAT + c4*4] = o;
  }
}

// ---- sparse prop: one wave per (dst,b); b=blockIdx&7 for XCD/L2 affinity ----
template<int SRC_OFF, int DST_OFF, int SECOND>
__global__ __launch_bounds__(64) void k_prop(_Float16* __restrict__ Acat,
                                             const int* __restrict__ rows,
                                             const float* __restrict__ norm,
                                             const unsigned int* __restrict__ count,
                                             const unsigned int* __restrict__ elist) {
  const int blk = blockIdx.x;
  const int b = blk & 7, dst = blk >> 3;
  const int lane = threadIdx.x;
  unsigned int cnt = count[dst]; if (cnt > 64u) cnt = 64u;
  const unsigned int* el = elist + dst*64;
  float a0 = 0.f, a1 = 0.f, a2 = 0.f, a3 = 0.f;
  for (unsigned int i = 0; i < cnt; ++i) {
    const unsigned int e = el[i];
    const int src = rows[e];
    const float nm = norm[e];
    half4 v = *(const half4*)&Acat[(size_t)(src*8 + b)*KCAT + SRC_OFF + lane*4];
    a0 += nm*(float)v[0]; a1 += nm*(float)v[1]; a2 += nm*(float)v[2]; a3 += nm*(float)v[3];
  }
  if (SECOND) {  // Tx2 = 2*prop(Tx1) - Tx0
    half4 hv = *(const half4*)&Acat[(size_t)(dst*8 + b)*KCAT + lane*4];
    a0 = 2.f*a0 - (float)hv[0]; a1 = 2.f*a1 - (float)hv[1];
    a2 = 2.f*a2 - (float)hv[2]; a3 = 2.f*a3 - (float)hv[3];
  }
  half4 o; o[0] = (_Float16)a0; o[1] = (_Float16)a1; o[2] = (_Float16)a2; o[3] = (_Float16)a3;
  *(half4*)&Acat[(size_t)(dst*8 + b)*KCAT + DST_OFF + lane*4] = o;
}

// ---- MFMA GEMM 64x64 tile: C = A[M,K] * Bt[n][k]^T; epilogue: bias(+gelu),
//      residual RMW on H, fused stats partials for the NEXT LayerNorm ----
template<int KSTEPS, int DO_GELU>
__global__ __launch_bounds__(256) void k_gemm(const _Float16* __restrict__ A,
                                              const _Float16* __restrict__ Bt, int ldb,
                                              const float* __restrict__ bias,
                                              float* __restrict__ H,
                                              float2* __restrict__ part) {
  __shared__ _Float16 Als[64*32];
  __shared__ _Float16 Bls[64*32];
  const int bm = blockIdx.x, bn = blockIdx.y;
  const int t = threadIdx.x;
  const int w = t >> 6, lane = t & 63;
  const int quad = lane >> 4, l16 = lane & 15;
  const int wm = w & 1, wn = w >> 1;   // wave tile: rows wm*32.., cols wn*32..

  f32x4 acc00 = {0.f,0.f,0.f,0.f};
  f32x4 acc01 = acc00, acc10 = acc00, acc11 = acc00;

  const int srow = t >> 2, sq = t & 3;        // staging: chunk t = 16B
  const _Float16* ga = A  + ((size_t)(bm*64 + srow)*KCAT + sq*8);
  const _Float16* gb = Bt + ((size_t)(bn*64 + srow)*ldb  + sq*8);
  _Float16* lA = &Als[w*512];   // wave-uniform LDS base; HW scatters lane*16B
  _Float16* lB = &Bls[w*512];

  for (int ks = 0; ks < KSTEPS; ++ks) {
    async_lds16(ga, lA);
    async_lds16(gb, lB);
    ga += 32; gb += 32;
    __syncthreads();
    half8 a0 = *(const half8*)&Als[(wm*32 +      l16)*32 + quad*8];
    half8 a1 = *(const half8*)&Als[(wm*32 + 16 + l16)*32 + quad*8];
    half8 b0 = *(const half8*)&Bls[(wn*32 +      l16)*32 + quad*8];
    half8 b1 = *(const half8*)&Bls[(wn*32 + 16 + l16)*32 + quad*8];
    acc00 = __builtin_amdgcn_mfma_f32_16x16x32_f16(a0, b0, acc00, 0, 0, 0);
    acc01 = __builtin_amdgcn_mfma_f32_16x16x32_f16(a0, b1, acc01, 0, 0, 0);
    acc10 = __builtin_amdgcn_mfma_f32_16x16x32_f16(a1, b0, acc10, 0, 0, 0);
    acc11 = __builtin_amdgcn_mfma_f32_16x16x32_f16(a1, b1, acc11, 0, 0, 0);
    __syncthreads();
  }

  float s = 0.f, s2 = 0.f;
  const int gm0 = bm*64 + wm*32, gn0 = bn*64 + wn*32;
  #pragma unroll
  for (int i = 0; i < 2; ++i) {
    #pragma unroll
    for (int j = 0; j < 2; ++j) {
      f32x4 a = (i == 0) ? (j == 0 ? acc00 : acc01) : (j == 0 ? acc10 : acc11);
      const int col = gn0 + j*16 + l16;
      const float bv = bias[col];
      #pragma unroll
      for (int r = 0; r < 4; ++r) {
        const int row = gm0 + i*16 + quad*4 + r;   // C/D: col=lane&15, row=quad*4+reg
        float v = a[r] + bv;
        if (DO_GELU) v = 0.5f*v*(1.f + erff(v*0.70710678118654752f));
        float hv = H[(size_t)row*CH + col] + v;
        H[(size_t)row*CH + col] = hv;
        s += hv; s2 += hv*hv;
      }
    }
  }
  __shared__ float red[512];
  red[t] = s; red[256+t] = s2; __syncthreads();
  for (int o = 128; o > 0; o >>= 1) {
    if (t < o) { red[t] += red[t+o]; red[256+t] += red[256+t+o]; }
    __syncthreads();
  }
  if (t == 0) part[blockIdx.y*gridDim.x + blockIdx.x] = make_float2(red[0], red[256]);
}

// ---- final mean over N ----
__global__ __launch_bounds__(256) void k_mean_part(const float* __restrict__ h,
                                                   float* __restrict__ mp) {
  int blk = blockIdx.x;          // 512 blocks: b = blk&7, chunk = blk>>3 (32 n's each)
  int b = blk & 7, chunk = blk >> 3;
  int c = threadIdx.x;
  float s = 0.f;
  for (int k = 0; k < 32; ++k) {
    int n = chunk*32 + k;
    s += h[((size_t)(n*8 + b) << 8) + c];
  }
  mp[((b*64 + chunk) << 8) + c] = s;
}

__global__ __launch_bounds__(256) void k_mean_final(const float* __restrict__ mp,
                                                    float* __restrict__ out) {
  int b = blockIdx.x, c = threadIdx.x;
  float s = 0.f;
  for (int ch = 0; ch < 64; ++ch) s += mp[((b*64 + ch) << 8) + c];
  out[(b << 8) + c] = s * (1.f/(float)NNODE);
}

extern "C" void kernel_launch(void* const* d_in, const int* in_sizes, int n_in,
                              void* d_out, int out_size, void* d_ws, size_t ws_size,
                              hipStream_t stream) {
  const float* x      = (const float*)d_in[0];   // node_feature [8,2048,256]
  const float* ew     = (const float*)d_in[1];   // edge_weight [3,32768]
  const float* cheb_w = (const float*)d_in[2];   // [3,3,256,256]
  const float* cheb_b = (const float*)d_in[3];   // [3,256]
  const float* mlp_w  = (const float*)d_in[4];   // [3,256,256]
  const float* mlp_b  = (const float*)d_in[5];   // [3,256]
  const int*   ei     = (const int*)d_in[6];     // [3,2,32768]
  float* out = (float*)d_out;

  char* ws = (char*)d_ws;
  float*        h     = (float*)(ws + OFF_H);
  _Float16*     Acat  = (_Float16*)(ws + OFF_ACAT);
  _Float16*     Wt    = (_Float16*)(ws + OFF_WT);
  _Float16*     Mt    = (_Float16*)(ws + OFF_MT);
  float2*       part  = (float2*)(ws + OFF_PART);
  float*        deg   = (float*)(ws + OFF_DEG);
  unsigned int* cnt   = (unsigned int*)(ws + OFF_CNT);
  unsigned int* elist = (unsigned int*)(ws + OFF_ELIST);
  float*        norm  = (float*)(ws + OFF_NORM);
  float*        mp    = (float*)(ws + OFF_MP);

  k_transpose<<<1024, 256, 0, stream>>>(x, h, part);
  k_weights<<<3072, 256, 0, stream>>>(cheb_w, mlp_w, Wt, Mt);
  k_edge_zero<<<24, 256, 0, stream>>>(deg, cnt);
  k_edge_scatter<<<(NLAYER*NEDGE)/256, 256, 0, stream>>>(ei, ew, deg, cnt, elist);
  k_edge_norm<<<(NLAYER*NEDGE)/256, 256, 0, stream>>>(ei, ew, deg, norm);

  for (int l = 0; l < NLAYER; ++l) {
    const int* rows_l = ei + l*2*NEDGE;
    const unsigned int* cnt_l = cnt + l*NNODE;
    const unsigned int* el_l  = elist + (size_t)l*NNODE*64;
    const float* norm_l = norm + l*NEDGE;

    // LN1 -> Acat[:,0:256] (Tx0)
    k_ln<<<1024, 256, 0, stream>>>(h, part, Acat);
    // Tx1 = prop(Tx0) -> Acat[:,256:512]
    k_prop<0, 256, 0><<<MROWS, 64, 0, stream>>>(Acat, rows_l, norm_l, cnt_l, el_l);
    // Tx2 = 2*prop(Tx1) - Tx0 -> Acat[:,512:768]
    k_prop<256, 512, 1><<<MROWS, 64, 0, stream>>>(Acat, rows_l, norm_l, cnt_l, el_l);
    // h += [Tx0|Tx1|Tx2] @ Wcat + cheb_b ; stats for LN2 -> part
    k_gemm<24, 0><<<dim3(256, 4), 256, 0, stream>>>(Acat, Wt + (size_t)l*CH*KCAT, KCAT,
                                                    cheb_b + l*CH, h, part);
    // LN2 -> Acat[:,0:256]
    k_ln<<<1024, 256, 0, stream>>>(h, part, Acat);
    // h += gelu(hn @ mlp_w + mlp_b) ; stats for next LN1 -> part
    k_gemm<8, 1><<<dim3(256, 4), 256, 0, stream>>>(Acat, Mt + (size_t)l*CH*CH, CH,
                                                   mlp_b + l*CH, h, part);
  }

  k_mean_part<<<512, 256, 0, stream>>>(h, mp);
  k_mean_final<<<8, 256, 0, stream>>>(mp, out);
}

// Round 2
// 320.494 us; speedup vs baseline: 1.2425x; 1.2425x over previous
//
#include <hip/hip_runtime.h>

#define BATCH   8
#define NNODE   2048
#define CH      256
#define NEDGE   32768
#define NLAYER  3
#define MROWS   (NNODE*BATCH)      // 16384 rows (n-major: row = n*8 + b)
#define KCAT    (3*CH)             // 768
#define NTOT    (MROWS*CH)         // 4,194,304 elements of h

typedef _Float16 half8 __attribute__((ext_vector_type(8)));
typedef _Float16 half4 __attribute__((ext_vector_type(4)));
typedef float    f32x4 __attribute__((ext_vector_type(4)));

// ---------------- workspace layout (bytes) ----------------
#define OFF_H      ((size_t)0)                    // fp32 h [MROWS][CH]            16,777,216
#define OFF_ACAT   ((size_t)16777216)             // f16 Acat [MROWS][KCAT]        25,165,824
#define OFF_WT     ((size_t)(16777216+25165824))  // f16 Wt [3][CH][KCAT] (folded)  1,179,648
#define OFF_MT     (OFF_WT + 1179648)             // f16 Mt [3][CH][CH]               393,216
#define OFF_PART   (OFF_MT + 393216)              // float2 part[1024]                  8,192
#define OFF_DEG    (OFF_PART + 8192)              // f32 deg[3][NNODE]                 24,576
#define OFF_CNT    (OFF_DEG + 24576)              // u32 count[3][NNODE]               24,576
#define OFF_ELIST  (OFF_CNT + 24576)              // u32 elist[3][NNODE][64]        1,572,864
#define OFF_NORM   (OFF_ELIST + 1572864)          // f32 norm[3][NEDGE]               393,216
#define OFF_MP     (OFF_NORM + 393216)            // f32 meanpart[8][64][CH]          524,288

__device__ __forceinline__ void async_lds16(const void* g, void* l) {
  __builtin_amdgcn_global_load_lds((const __attribute__((address_space(1))) void*)g,
                                   (__attribute__((address_space(3))) void*)l, 16, 0, 0);
}

// ---- init: transpose [B,N,C]->[N,B,C] + LN0 stats | fold+convert weights | zero deg/cnt ----
__global__ __launch_bounds__(256) void k_init(const float* __restrict__ x,
                                              float* __restrict__ h,
                                              float2* __restrict__ part,
                                              const float* __restrict__ cheb_w,
                                              const float* __restrict__ mlp_w,
                                              _Float16* __restrict__ Wt,
                                              _Float16* __restrict__ Mt,
                                              float* __restrict__ deg,
                                              unsigned int* __restrict__ count) {
  const int blk = blockIdx.x;
  if (blk < 1024) {
    int tid = blk*256 + threadIdx.x;
    float s = 0.f, s2 = 0.f;
    for (int i = tid; i < NTOT/4; i += 1024*256) {
      int c4 = i & 63, b = (i >> 6) & 7, n = i >> 9;
      float4 v = ((const float4*)x)[((b*NNODE + n) << 6) + c4];
      ((float4*)h)[i] = v;
      s  += v.x + v.y + v.z + v.w;
      s2 += v.x*v.x + v.y*v.y + v.z*v.z + v.w*v.w;
    }
    __shared__ float rs[512];
    rs[threadIdx.x] = s; rs[256+threadIdx.x] = s2; __syncthreads();
    for (int o = 128; o > 0; o >>= 1) {
      if (threadIdx.x < o) { rs[threadIdx.x] += rs[threadIdx.x+o]; rs[256+threadIdx.x] += rs[256+threadIdx.x+o]; }
      __syncthreads();
    }
    if (threadIdx.x == 0) part[blk] = make_float2(rs[0], rs[256]);
  } else if (blk < 4096) {
    int i = (blk - 1024)*256 + threadIdx.x;
    const int nc = NLAYER*CH*KCAT;  // 589,824
    if (i < nc) {
      int l = i / (CH*KCAT), r = i % (CH*KCAT);
      int n = r / KCAT, k = r % KCAT;
      int kk = k >> 8, cin = k & 255;
      // fold: [W0-W2 ; W1 ; 2*W2]  (so prop2 stores plain P2=prop(Tx1))
      float w1v = cheb_w[((l*3 + kk)*CH + cin)*CH + n];
      float v;
      if (kk == 0)       v = w1v - cheb_w[((l*3 + 2)*CH + cin)*CH + n];
      else if (kk == 1)  v = w1v;
      else               v = 2.f*w1v;
      Wt[i] = (_Float16)v;
    } else {
      int j = i - nc;
      if (j < NLAYER*CH*CH) {
        int l = j / (CH*CH), r = j % (CH*CH);
        int n = r >> 8, k = r & 255;
        Mt[j] = (_Float16)mlp_w[(l*CH + k)*CH + n];
      }
    }
  } else {
    int i = (blk - 4096)*256 + threadIdx.x;
    if (i < NLAYER*NNODE) { deg[i] = 0.f; count[i] = 0u; }
  }
}

__global__ __launch_bounds__(256) void k_edge_scatter(const int* __restrict__ ei,
                                                      const float* __restrict__ ew,
                                                      float* deg, unsigned int* count,
                                                      unsigned int* elist) {
  int i = blockIdx.x*256 + threadIdx.x;
  if (i >= NLAYER*NEDGE) return;
  int l = i / NEDGE, e = i % NEDGE;
  const int* rows = ei + l*2*NEDGE;
  const int* cols = rows + NEDGE;
  int r = rows[e], c = cols[e];
  float w = (r == c) ? 0.f : ew[l*NEDGE + e];
  atomicAdd(&deg[l*NNODE + r], w);
  unsigned int slot = atomicAdd(&count[l*NNODE + c], 1u);
  if (slot < 64u) elist[(l*NNODE + c)*64 + slot] = (unsigned int)e;
}

__global__ __launch_bounds__(256) void k_edge_norm(const int* __restrict__ ei,
                                                   const float* __restrict__ ew,
                                                   const float* __restrict__ deg,
                                                   float* __restrict__ norm) {
  int i = blockIdx.x*256 + threadIdx.x;
  if (i >= NLAYER*NEDGE) return;
  int l = i / NEDGE, e = i % NEDGE;
  const int* rows = ei + l*2*NEDGE;
  const int* cols = rows + NEDGE;
  int r = rows[e], c = cols[e];
  float w = (r == c) ? 0.f : ew[l*NEDGE + e];
  float dr = deg[l*NNODE + r], dc = deg[l*NNODE + c];
  float ir = dr > 0.f ? rsqrtf(fmaxf(dr, 1e-12f)) : 0.f;
  float ic = dc > 0.f ? rsqrtf(fmaxf(dc, 1e-12f)) : 0.f;
  norm[i] = -(ir * w * ic);
}

// ---- whole-tensor LN: reduce 1024 partials, write f16 hn into Acat[:,0:256] ----
__global__ __launch_bounds__(256) void k_ln(const float* __restrict__ h,
                                            const float2* __restrict__ part,
                                            _Float16* __restrict__ Acat) {
  __shared__ float red[512];
  float s = 0.f, s2 = 0.f;
  for (int i = threadIdx.x; i < 1024; i += 256) { float2 p = part[i]; s += p.x; s2 += p.y; }
  red[threadIdx.x] = s; red[256+threadIdx.x] = s2; __syncthreads();
  for (int o = 128; o > 0; o >>= 1) {
    if (threadIdx.x < o) { red[threadIdx.x] += red[threadIdx.x+o]; red[256+threadIdx.x] += red[256+threadIdx.x+o]; }
    __syncthreads();
  }
  __shared__ float mv[2];
  if (threadIdx.x == 0) {
    float mean = red[0] * (1.f/(float)NTOT);
    float var  = red[256] * (1.f/(float)NTOT) - mean*mean;
    mv[0] = mean; mv[1] = rsqrtf(var + 1e-5f);
  }
  __syncthreads();
  const float mean = mv[0], istd = mv[1];
  const float4* h4 = (const float4*)h;
  for (int i = blockIdx.x*256 + threadIdx.x; i < NTOT/8; i += 1024*256) {
    float4 v0 = h4[2*i], v1 = h4[2*i+1];
    int r = i >> 5, c8 = i & 31;
    half8 o;
    o[0] = (_Float16)((v0.x - mean)*istd); o[1] = (_Float16)((v0.y - mean)*istd);
    o[2] = (_Float16)((v0.z - mean)*istd); o[3] = (_Float16)((v0.w - mean)*istd);
    o[4] = (_Float16)((v1.x - mean)*istd); o[5] = (_Float16)((v1.y - mean)*istd);
    o[6] = (_Float16)((v1.z - mean)*istd); o[7] = (_Float16)((v1.w - mean)*istd);
    *(half8*)&Acat[(size_t)r*KCAT + c8*8] = o;
  }
}

// ---- sparse prop: one wave per (dst,b); metadata lane-parallel, readlane broadcast ----
template<int SRC_OFF, int DST_OFF>
__global__ __launch_bounds__(64) void k_prop(_Float16* __restrict__ Acat,
                                             const int* __restrict__ rows,
                                             const float* __restrict__ norm,
                                             const unsigned int* __restrict__ count,
                                             const unsigned int* __restrict__ elist) {
  const int blk = blockIdx.x;
  const int b = blk & 7, dst = blk >> 3;   // b = blk&7 -> XCD/L2 affinity per batch slice
  const int lane = threadIdx.x;
  unsigned int cnt = count[dst]; if (cnt > 64u) cnt = 64u;
  // lane-parallel metadata prefetch: lane i holds edge i's (src, norm)
  int   srcv = 0;
  float nmv  = 0.f;
  if (lane < (int)cnt) {
    unsigned int e = elist[dst*64 + lane];
    srcv = rows[e];
    nmv  = norm[e];
  }
  float a0 = 0.f, a1 = 0.f, a2 = 0.f, a3 = 0.f;
  const _Float16* base = Acat + SRC_OFF + lane*4;
  #define PROP_STEP(i)                                                              \
    {                                                                               \
      int   src = __builtin_amdgcn_readlane(srcv, (i));                             \
      int   nbi = __builtin_amdgcn_readlane(__builtin_bit_cast(int, nmv), (i));     \
      float nm  = __builtin_bit_cast(float, nbi);                                   \
      half4 v = *(const half4*)&base[(size_t)(src*8 + b)*KCAT];                     \
      a0 += nm*(float)v[0]; a1 += nm*(float)v[1];                                   \
      a2 += nm*(float)v[2]; a3 += nm*(float)v[3];                                   \
    }
  unsigned int i = 0;
  for (; i + 4 <= cnt; i += 4) { PROP_STEP(i) PROP_STEP(i+1) PROP_STEP(i+2) PROP_STEP(i+3) }
  for (; i < cnt; ++i) { PROP_STEP(i) }
  #undef PROP_STEP
  half4 o; o[0] = (_Float16)a0; o[1] = (_Float16)a1; o[2] = (_Float16)a2; o[3] = (_Float16)a3;
  *(half4*)&Acat[(size_t)(dst*8 + b)*KCAT + DST_OFF + lane*4] = o;
}

// ---- MFMA GEMM 64x64 tile, BK=64, XOR-swizzled LDS (conflict-free ds_read_b128).
//      Epilogue: bias(+gelu), residual RMW on H, fused stats for the next LN. ----
template<int KSTEPS, int DO_GELU>
__global__ __launch_bounds__(256) void k_gemm(const _Float16* __restrict__ A, int lda,
                                              const _Float16* __restrict__ Bt, int ldb,
                                              const float* __restrict__ bias,
                                              float* __restrict__ H,
                                              float2* __restrict__ part) {
  __shared__ _Float16 Als[64*64];   // 8 KB
  __shared__ _Float16 Bls[64*64];   // 8 KB
  const int bm = blockIdx.x, bn = blockIdx.y;
  const int t = threadIdx.x;
  const int w = t >> 6, lane = t & 63;
  const int quad = lane >> 4, l16 = lane & 15;
  const int wm = w & 1, wn = w >> 1;   // wave tile: 32x32

  f32x4 acc00 = {0.f,0.f,0.f,0.f};
  f32x4 acc01 = acc00, acc10 = acc00, acc11 = acc00;

  // staging: 2 issues per tile per ks; chunk c = j*256 + w*64 + lane (16B each)
  // global fetch is XOR-swizzled by row so LDS seg s holds global kseg s^(row&7)
  const int c0 = w*64 + lane, c1 = 256 + w*64 + lane;
  const int r0 = c0 >> 3, s0 = (c0 & 7) ^ (r0 & 7);
  const int r1 = c1 >> 3, s1 = (c1 & 7) ^ (r1 & 7);
  const _Float16* ga0 = A  + (size_t)(bm*64 + r0)*lda + s0*8;
  const _Float16* ga1 = A  + (size_t)(bm*64 + r1)*lda + s1*8;
  const _Float16* gb0 = Bt + (size_t)(bn*64 + r0)*ldb + s0*8;
  const _Float16* gb1 = Bt + (size_t)(bn*64 + r1)*ldb + s1*8;
  _Float16* lA0 = &Als[w*512];        // wave-uniform bases; HW scatters lane*16B
  _Float16* lA1 = &Als[2048 + w*512];
  _Float16* lB0 = &Bls[w*512];
  _Float16* lB1 = &Bls[2048 + w*512];

  const int ra0 = wm*32 + l16, ra1 = ra0 + 16;
  const int rb0 = wn*32 + l16, rb1 = rb0 + 16;

  for (int ks = 0; ks < KSTEPS; ++ks) {
    async_lds16(ga0, lA0); async_lds16(ga1, lA1);
    async_lds16(gb0, lB0); async_lds16(gb1, lB1);
    ga0 += 64; ga1 += 64; gb0 += 64; gb1 += 64;
    __syncthreads();
    #pragma unroll
    for (int kh = 0; kh < 2; ++kh) {   // k-half: global kseg = kh*4 + quad
      const int q = kh*4 + quad;
      half8 a0 = *(const half8*)&Als[ra0*64 + ((q ^ (ra0 & 7)))*8];
      half8 a1 = *(const half8*)&Als[ra1*64 + ((q ^ (ra1 & 7)))*8];
      half8 b0 = *(const half8*)&Bls[rb0*64 + ((q ^ (rb0 & 7)))*8];
      half8 b1 = *(const half8*)&Bls[rb1*64 + ((q ^ (rb1 & 7)))*8];
      acc00 = __builtin_amdgcn_mfma_f32_16x16x32_f16(a0, b0, acc00, 0, 0, 0);
      acc01 = __builtin_amdgcn_mfma_f32_16x16x32_f16(a0, b1, acc01, 0, 0, 0);
      acc10 = __builtin_amdgcn_mfma_f32_16x16x32_f16(a1, b0, acc10, 0, 0, 0);
      acc11 = __builtin_amdgcn_mfma_f32_16x16x32_f16(a1, b1, acc11, 0, 0, 0);
    }
    __syncthreads();
  }

  float s = 0.f, s2 = 0.f;
  const int gm0 = bm*64 + wm*32, gn0 = bn*64 + wn*32;
  #pragma unroll
  for (int i = 0; i < 2; ++i) {
    #pragma unroll
    for (int j = 0; j < 2; ++j) {
      f32x4 a = (i == 0) ? (j == 0 ? acc00 : acc01) : (j == 0 ? acc10 : acc11);
      const int col = gn0 + j*16 + l16;
      const float bv = bias[col];
      #pragma unroll
      for (int r = 0; r < 4; ++r) {
        const int row = gm0 + i*16 + quad*4 + r;   // C/D: col=lane&15, row=quad*4+reg
        float v = a[r] + bv;
        if (DO_GELU) v = 0.5f*v*(1.f + erff(v*0.70710678118654752f));
        float hv = H[(size_t)row*CH + col] + v;
        H[(size_t)row*CH + col] = hv;
        s += hv; s2 += hv*hv;
      }
    }
  }
  __shared__ float red[512];
  red[t] = s; red[256+t] = s2; __syncthreads();
  for (int o = 128; o > 0; o >>= 1) {
    if (t < o) { red[t] += red[t+o]; red[256+t] += red[256+t+o]; }
    __syncthreads();
  }
  if (t == 0) part[blockIdx.y*gridDim.x + blockIdx.x] = make_float2(red[0], red[256]);
}

// ---- final mean over N ----
__global__ __launch_bounds__(256) void k_mean_part(const float* __restrict__ h,
                                                   float* __restrict__ mp) {
  int blk = blockIdx.x;          // 512 blocks: b = blk&7, chunk = blk>>3 (32 n's each)
  int b = blk & 7, chunk = blk >> 3;
  int c = threadIdx.x;
  float s = 0.f;
  for (int k = 0; k < 32; ++k) {
    int n = chunk*32 + k;
    s += h[((size_t)(n*8 + b) << 8) + c];
  }
  mp[((b*64 + chunk) << 8) + c] = s;
}

__global__ __launch_bounds__(256) void k_mean_final(const float* __restrict__ mp,
                                                    float* __restrict__ out) {
  int b = blockIdx.x, c = threadIdx.x;
  float s = 0.f;
  for (int ch = 0; ch < 64; ++ch) s += mp[((b*64 + ch) << 8) + c];
  out[(b << 8) + c] = s * (1.f/(float)NNODE);
}

extern "C" void kernel_launch(void* const* d_in, const int* in_sizes, int n_in,
                              void* d_out, int out_size, void* d_ws, size_t ws_size,
                              hipStream_t stream) {
  const float* x      = (const float*)d_in[0];   // node_feature [8,2048,256]
  const float* ew     = (const float*)d_in[1];   // edge_weight [3,32768]
  const float* cheb_w = (const float*)d_in[2];   // [3,3,256,256]
  const float* cheb_b = (const float*)d_in[3];   // [3,256]
  const float* mlp_w  = (const float*)d_in[4];   // [3,256,256]
  const float* mlp_b  = (const float*)d_in[5];   // [3,256]
  const int*   ei     = (const int*)d_in[6];     // [3,2,32768]
  float* out = (float*)d_out;

  char* ws = (char*)d_ws;
  float*        h     = (float*)(ws + OFF_H);
  _Float16*     Acat  = (_Float16*)(ws + OFF_ACAT);
  _Float16*     Wt    = (_Float16*)(ws + OFF_WT);
  _Float16*     Mt    = (_Float16*)(ws + OFF_MT);
  float2*       part  = (float2*)(ws + OFF_PART);
  float*        deg   = (float*)(ws + OFF_DEG);
  unsigned int* cnt   = (unsigned int*)(ws + OFF_CNT);
  unsigned int* elist = (unsigned int*)(ws + OFF_ELIST);
  float*        norm  = (float*)(ws + OFF_NORM);
  float*        mp    = (float*)(ws + OFF_MP);

  k_init<<<4120, 256, 0, stream>>>(x, h, part, cheb_w, mlp_w, Wt, Mt, deg, cnt);
  k_edge_scatter<<<(NLAYER*NEDGE)/256, 256, 0, stream>>>(ei, ew, deg, cnt, elist);
  k_edge_norm<<<(NLAYER*NEDGE)/256, 256, 0, stream>>>(ei, ew, deg, norm);

  for (int l = 0; l < NLAYER; ++l) {
    const int* rows_l = ei + l*2*NEDGE;
    const unsigned int* cnt_l = cnt + l*NNODE;
    const unsigned int* el_l  = elist + (size_t)l*NNODE*64;
    const float* norm_l = norm + l*NEDGE;

    // LN1 -> Acat[:,0:256] (Tx0)
    k_ln<<<1024, 256, 0, stream>>>(h, part, Acat);
    // Tx1 = prop(Tx0) -> Acat[:,256:512]
    k_prop<0, 256><<<MROWS, 64, 0, stream>>>(Acat, rows_l, norm_l, cnt_l, el_l);
    // P2 = prop(Tx1) -> Acat[:,512:768]   (weights folded: no Tx0 subtraction here)
    k_prop<256, 512><<<MROWS, 64, 0, stream>>>(Acat, rows_l, norm_l, cnt_l, el_l);
    // h += [Tx0|Tx1|P2] @ [W0-W2;W1;2W2] + cheb_b ; stats for LN2 -> part
    k_gemm<12, 0><<<dim3(256, 4), 256, 0, stream>>>(Acat, KCAT, Wt + (size_t)l*CH*KCAT, KCAT,
                                                    cheb_b + l*CH, h, part);
    // LN2 -> Acat[:,0:256]
    k_ln<<<1024, 256, 0, stream>>>(h, part, Acat);
    // h += gelu(hn @ mlp_w + mlp_b) ; stats for next LN1 -> part
    k_gemm<4, 1><<<dim3(256, 4), 256, 0, stream>>>(Acat, KCAT, Mt + (size_t)l*CH*CH, CH,
                                                   mlp_b + l*CH, h, part);
  }

  k_mean_part<<<512, 256, 0, stream>>>(h, mp);
  k_mean_final<<<8, 256, 0, stream>>>(mp, out);
}